// Round 3
// baseline (1541.754 us; speedup 1.0000x reference)
//
#include <hip/hip_runtime.h>
#include <stdint.h>

#define SEQ 32768
#define DIM 1024
#define FFD 4096
#define NE 8
#define CAP 5120

typedef __bf16 bf16x8 __attribute__((ext_vector_type(8)));
typedef float f32x4 __attribute__((ext_vector_type(4)));

__device__ __forceinline__ short f2bf(float f) {
  uint32_t u = __float_as_uint(f);
  uint32_t r = (u + 0x7fffu + ((u >> 16) & 1u)) >> 16;
  return (short)r;
}

__device__ __forceinline__ void async_copy16(const void* g, void* lds) {
  __builtin_amdgcn_global_load_lds((const __attribute__((address_space(1))) void*)g,
                                   (__attribute__((address_space(3))) void*)lds, 16, 0, 0);
}

// A&S 7.1.26 erf: max abs err 1.5e-7, branchless
__device__ __forceinline__ float fast_erf(float y) {
  float ay = fabsf(y);
  float t = __frcp_rn(1.0f + 0.3275911f * ay);
  float p = 1.061405429f;
  p = p * t - 1.453152027f;
  p = p * t + 1.421413741f;
  p = p * t - 0.284496736f;
  p = p * t + 0.254829592f;
  p = p * t;
  float e = __expf(-ay * ay);
  float r = 1.0f - p * e;
  return copysignf(r, y);
}

// ---------------- router: logits in f64, argmax + p_max ----------------
__global__ __launch_bounds__(256) void moe_router(const float* __restrict__ x,
                                                  const float* __restrict__ Wg,
                                                  const float* __restrict__ bg,
                                                  int* __restrict__ routes,
                                                  float* __restrict__ pmax) {
  int token = blockIdx.x * 4 + (threadIdx.x >> 6);
  int lane = threadIdx.x & 63;
  const float* xr = x + (size_t)token * DIM;
  double acc[NE];
#pragma unroll
  for (int e = 0; e < NE; e++) acc[e] = 0.0;
#pragma unroll
  for (int i = 0; i < DIM / 64; i++) {
    int d = i * 64 + lane;
    double xv = (double)xr[d];
    const float* wr = Wg + (size_t)d * NE;
    float4 w0 = *(const float4*)(wr);
    float4 w1 = *(const float4*)(wr + 4);
    acc[0] += xv * (double)w0.x; acc[1] += xv * (double)w0.y;
    acc[2] += xv * (double)w0.z; acc[3] += xv * (double)w0.w;
    acc[4] += xv * (double)w1.x; acc[5] += xv * (double)w1.y;
    acc[6] += xv * (double)w1.z; acc[7] += xv * (double)w1.w;
  }
#pragma unroll
  for (int e = 0; e < NE; e++) {
#pragma unroll
    for (int off = 32; off >= 1; off >>= 1) acc[e] += __shfl_xor(acc[e], off);
  }
  if (lane == 0) {
    double l[NE];
#pragma unroll
    for (int e = 0; e < NE; e++) l[e] = acc[e] + (double)bg[e];
    int am = 0;
#pragma unroll
    for (int e = 1; e < NE; e++) if (l[e] > l[am]) am = e;
    double s = 0.0;
#pragma unroll
    for (int e = 0; e < NE; e++) s += exp(l[e] - l[am]);
    routes[token] = am;
    pmax[token] = (float)(1.0 / s);
  }
}

// ---------------- scan: per-expert FCFS positions ----------------
__global__ __launch_bounds__(1024) void moe_scan(const int* __restrict__ routes,
                                                 int* __restrict__ slot_of_token,
                                                 int* __restrict__ token_of_slot,
                                                 int* __restrict__ counts) {
  __shared__ int wtot[16][NE];
  __shared__ int woff[16][NE];
  int t = threadIdx.x, lane = t & 63, w = t >> 6;
  int cnt[NE];
#pragma unroll
  for (int e = 0; e < NE; e++) cnt[e] = 0;
  int base = t * 32;
  for (int i = 0; i < 32; i++) {
    int r = routes[base + i];
#pragma unroll
    for (int e = 0; e < NE; e++) cnt[e] += (r == e) ? 1 : 0;
  }
  int incl[NE];
#pragma unroll
  for (int e = 0; e < NE; e++) {
    int v = cnt[e];
#pragma unroll
    for (int off = 1; off < 64; off <<= 1) {
      int o = __shfl_up(v, off);
      if (lane >= off) v += o;
    }
    incl[e] = v;
    if (lane == 63) wtot[w][e] = v;
  }
  __syncthreads();
  if (t < NE) {
    int run = 0;
    for (int ww = 0; ww < 16; ww++) {
      int tmp = wtot[ww][t];
      woff[ww][t] = run;
      run += tmp;
    }
    counts[t] = run;
  }
  __syncthreads();
  int pos[NE];
#pragma unroll
  for (int e = 0; e < NE; e++) pos[e] = woff[w][e] + incl[e] - cnt[e];
  for (int i = 0; i < 32; i++) {
    int tok = base + i;
    int r = routes[tok];
    int p = 0;
#pragma unroll
    for (int e = 0; e < NE; e++)
      if (r == e) { p = pos[e]; pos[e] = p + 1; }
    bool kept = p < CAP;
    int slot = kept ? r * CAP + p : NE * CAP;
    slot_of_token[tok] = slot;
    if (kept) token_of_slot[slot] = tok;
  }
}

// ---------------- gather dispatch buffer (bf16), zeros for empty slots ----------------
__global__ __launch_bounds__(256) void moe_gather(const float* __restrict__ x,
                                                  const int* __restrict__ token_of_slot,
                                                  short* __restrict__ Xd) {
  int slot = blockIdx.x;
  int tok = token_of_slot[slot];
  int t = threadIdx.x;
  short* dst = Xd + (size_t)slot * DIM + t * 4;
  short4 v;
  if (tok < 0) {
    v.x = 0; v.y = 0; v.z = 0; v.w = 0;
  } else {
    float4 f = *(const float4*)(x + (size_t)tok * DIM + t * 4);
    v.x = f2bf(f.x); v.y = f2bf(f.y); v.z = f2bf(f.z); v.w = f2bf(f.w);
  }
  *(short4*)dst = v;
}

// ---------------- convert f32 [E][K][N] -> bf16 [E][N][K] ----------------
__global__ __launch_bounds__(256) void moe_convT(const float* __restrict__ W,
                                                 short* __restrict__ WT, int K, int N) {
  __shared__ float tile[32][33];
  int e = blockIdx.z;
  const float* We = W + (size_t)e * K * N;
  short* WTe = WT + (size_t)e * K * N;
  int n0 = blockIdx.x * 32, k0 = blockIdx.y * 32;
  int tx = threadIdx.x, ty = threadIdx.y;
#pragma unroll
  for (int i = 0; i < 4; i++)
    tile[ty + i * 8][tx] = We[(size_t)(k0 + ty + i * 8) * N + n0 + tx];
  __syncthreads();
#pragma unroll
  for (int i = 0; i < 4; i++)
    WTe[(size_t)(n0 + ty + i * 8) * K + k0 + tx] = f2bf(tile[tx][ty + i * 8]);
}

// ---------------- GEMM mainloop: C[128x128] += A[128xK] * BT[128xK]^T ----------------
__device__ __forceinline__ void gemm_mainloop(const short* Ag, const short* Bg,
                                              int lda, int ldb, int K,
                                              short* As, short* Bs, f32x4 acc[4][4]) {
  int t = threadIdx.x;
  int lane = t & 63;
  int wv = t >> 6;
  int wr = wv >> 1, wc = wv & 1;
  int lrow = lane & 15, kh = lane >> 4;
  int sr = t >> 3;
  int sc = (t & 7) * 8;
  for (int kt = 0; kt < K; kt += 64) {
    const short* Ak = Ag + kt;
    const short* Bk = Bg + kt;
#pragma unroll
    for (int i = 0; i < 4; i++) {
      async_copy16(Ak + (size_t)(i * 32 + sr) * lda + sc, As + t * 8 + i * 2048);
      async_copy16(Bk + (size_t)(i * 32 + sr) * ldb + sc, Bs + t * 8 + i * 2048);
    }
    __syncthreads();
#pragma unroll
    for (int kk = 0; kk < 2; kk++) {
      bf16x8 a[4], b[4];
#pragma unroll
      for (int mi = 0; mi < 4; mi++)
        a[mi] = *(const bf16x8*)(As + (wr * 64 + mi * 16 + lrow) * 64 + kk * 32 + kh * 8);
#pragma unroll
      for (int ni = 0; ni < 4; ni++)
        b[ni] = *(const bf16x8*)(Bs + (wc * 64 + ni * 16 + lrow) * 64 + kk * 32 + kh * 8);
#pragma unroll
      for (int mi = 0; mi < 4; mi++)
#pragma unroll
        for (int ni = 0; ni < 4; ni++)
          acc[mi][ni] = __builtin_amdgcn_mfma_f32_16x16x32_bf16(a[mi], b[ni], acc[mi][ni], 0, 0, 0);
    }
    __syncthreads();
  }
}

// ---------------- GEMM1: h = gelu(Xd @ W1 + b1), swizzled grid, LDS-staged write ------
// grid.x = 32 * (8*mch); decode: xcd-major so all 32 N-blocks of one M-slab share an XCD
__global__ __launch_bounds__(256) void moe_gemm1(const short* __restrict__ Xd,
                                                 const short* __restrict__ W1bT,
                                                 const float* __restrict__ b1,
                                                 short* __restrict__ h,
                                                 const int* __restrict__ counts,
                                                 int m_base, int rows, int mch) {
  __shared__ short smem[128 * 128];
  short* As = smem;
  short* Bs = smem + 128 * 64;
  int bid = blockIdx.x;
  int xcd = bid & 7;
  int idx = bid >> 3;
  int nn = idx & 31;            // 32 N-blocks
  int mg = idx >> 5;
  int mlin = mg * 8 + xcd;      // 0 .. 8*mch-1
  int e = mlin / mch;
  int mm = mlin % mch;
  int cnt = counts[e]; if (cnt > CAP) cnt = CAP;
  int m0 = m_base + mm * 128;
  if (m0 >= cnt) return;
  int n0 = nn * 128;
  const short* Ag = Xd + ((size_t)e * CAP + m0) * DIM;
  const short* Bg = W1bT + ((size_t)e * FFD + n0) * DIM;
  f32x4 acc[4][4];
#pragma unroll
  for (int mi = 0; mi < 4; mi++)
#pragma unroll
    for (int ni = 0; ni < 4; ni++) acc[mi][ni] = (f32x4){0.f, 0.f, 0.f, 0.f};
  gemm_mainloop(Ag, Bg, DIM, DIM, DIM, As, Bs, acc);

  int t = threadIdx.x, lane = t & 63, wv = t >> 6;
  int wr = wv >> 1, wc = wv & 1;
  int col_l = lane & 15, row_q = lane >> 4;
  float bias[4];
  int lc[4];
#pragma unroll
  for (int ni = 0; ni < 4; ni++) {
    lc[ni] = wc * 64 + ni * 16 + col_l;
    bias[ni] = b1[(size_t)e * FFD + n0 + lc[ni]];
  }
#pragma unroll
  for (int mi = 0; mi < 4; mi++) {
#pragma unroll
    for (int j = 0; j < 4; j++) {
      int lr = wr * 64 + mi * 16 + row_q * 4 + j;
#pragma unroll
      for (int ni = 0; ni < 4; ni++) {
        float v = acc[mi][ni][j] + bias[ni];
        float g = 0.5f * v * (1.0f + fast_erf(v * 0.70710678118654752f));
        smem[lr * 128 + lc[ni]] = f2bf(g);
      }
    }
  }
  __syncthreads();
  short* he = h + ((size_t)e * rows + mm * 128) * FFD + n0;
  int rr = t >> 4, cc = (t & 15) * 8;
#pragma unroll
  for (int i = 0; i < 8; i++) {
    int r = i * 16 + rr;
    *(int4*)(he + (size_t)r * FFD + cc) = *(const int4*)(smem + r * 128 + cc);
  }
}

// ---------------- GEMM2: out[token] = (h @ W2 + b2) * p_max, swizzled grid ------------
// grid.x = 8 * (8*mch); all 8 N-blocks of one M-slab share an XCD -> A-panel L2 hit
__global__ __launch_bounds__(256) void moe_gemm2(const short* __restrict__ h,
                                                 const short* __restrict__ W2bT,
                                                 const float* __restrict__ b2,
                                                 const int* __restrict__ token_of_slot,
                                                 const float* __restrict__ pmax,
                                                 float* __restrict__ out,
                                                 const int* __restrict__ counts,
                                                 int m_base, int rows, int mch) {
  __shared__ short smem[128 * 128];
  short* As = smem;
  short* Bs = smem + 128 * 64;
  float* smemF = (float*)smem;
  int bid = blockIdx.x;
  int xcd = bid & 7;
  int idx = bid >> 3;
  int nn = idx & 7;             // 8 N-blocks
  int mg = idx >> 3;
  int mlin = mg * 8 + xcd;
  int e = mlin / mch;
  int mm = mlin % mch;
  int cnt = counts[e]; if (cnt > CAP) cnt = CAP;
  int m0 = m_base + mm * 128;
  if (m0 >= cnt) return;
  int n0 = nn * 128;
  const short* Ag = h + ((size_t)e * rows + mm * 128) * FFD;
  const short* Bg = W2bT + ((size_t)e * DIM + n0) * FFD;
  f32x4 acc[4][4];
#pragma unroll
  for (int mi = 0; mi < 4; mi++)
#pragma unroll
    for (int ni = 0; ni < 4; ni++) acc[mi][ni] = (f32x4){0.f, 0.f, 0.f, 0.f};
  gemm_mainloop(Ag, Bg, FFD, FFD, FFD, As, Bs, acc);

  int t = threadIdx.x, lane = t & 63, wv = t >> 6;
  int wr = wv >> 1, wc = wv & 1;
  int col_l = lane & 15, row_q = lane >> 4;
  float bias[4];
  int lc[4];
#pragma unroll
  for (int ni = 0; ni < 4; ni++) {
    lc[ni] = wc * 64 + ni * 16 + col_l;
    bias[ni] = b2[(size_t)e * DIM + n0 + lc[ni]];
  }
#pragma unroll
  for (int half = 0; half < 2; half++) {
    if (wr == half) {
#pragma unroll
      for (int mi = 0; mi < 4; mi++) {
#pragma unroll
        for (int j = 0; j < 4; j++) {
          int lr = mi * 16 + row_q * 4 + j;
#pragma unroll
          for (int ni = 0; ni < 4; ni++)
            smemF[lr * 128 + lc[ni]] = acc[mi][ni][j] + bias[ni];
        }
      }
    }
    __syncthreads();
    int r32 = t >> 5, c32 = (t & 31) * 4;
#pragma unroll
    for (int i = 0; i < 8; i++) {
      int r = i * 8 + r32;
      int tok = token_of_slot[e * CAP + m0 + half * 64 + r];
      if (tok >= 0) {
        float f = pmax[tok];
        float4 v = *(const float4*)(smemF + r * 128 + c32);
        v.x *= f; v.y *= f; v.z *= f; v.w *= f;
        *(float4*)(out + (size_t)tok * DIM + n0 + c32) = v;
      }
    }
    __syncthreads();
  }
}

// ---------------- dropped tokens: passthrough x ----------------
__global__ __launch_bounds__(256) void moe_fixup(const float* __restrict__ x,
                                                 const int* __restrict__ slot_of_token,
                                                 float* __restrict__ out) {
  int tok8 = blockIdx.x * 8 + (threadIdx.x >> 5);
  int lane32 = threadIdx.x & 31;
  if (slot_of_token[tok8] != NE * CAP) return;
#pragma unroll
  for (int i = 0; i < 8; i++) {
    int c = (i * 32 + lane32) * 4;
    float4 v = *(const float4*)(x + (size_t)tok8 * DIM + c);
    *(float4*)(out + (size_t)tok8 * DIM + c) = v;
  }
}

extern "C" void kernel_launch(void* const* d_in, const int* in_sizes, int n_in,
                              void* d_out, int out_size, void* d_ws, size_t ws_size,
                              hipStream_t stream) {
  (void)in_sizes; (void)n_in; (void)out_size;
  const float* x  = (const float*)d_in[0];
  const float* Wg = (const float*)d_in[1];
  const float* bg = (const float*)d_in[2];
  const float* W1 = (const float*)d_in[3];
  const float* b1 = (const float*)d_in[4];
  const float* W2 = (const float*)d_in[5];
  const float* b2 = (const float*)d_in[6];
  float* out = (float*)d_out;

  char* p = (char*)d_ws;
  auto carve = [&](size_t bytes) -> char* {
    char* r = p;
    p += (bytes + 255) & ~(size_t)255;
    return r;
  };
  short* W1bT = (short*)carve((size_t)NE * DIM * FFD * 2);
  short* W2bT = (short*)carve((size_t)NE * DIM * FFD * 2);
  short* Xd   = (short*)carve((size_t)NE * CAP * DIM * 2);
  int* routes = (int*)carve((size_t)SEQ * 4);
  float* pmax = (float*)carve((size_t)SEQ * 4);
  int* slot_of_token = (int*)carve((size_t)SEQ * 4);
  int* token_of_slot = (int*)carve((size_t)(NE * CAP) * 4);
  int* counts = (int*)carve(256);
  size_t fixed = (size_t)(p - (char*)d_ws);

  // h chunk: target 1280 rows/expert (80 MB -> L3-resident between gemm1 and gemm2)
  size_t avail = (ws_size > fixed + 4096) ? (ws_size - fixed - 4096) : 0;
  size_t per_row = (size_t)NE * FFD * 2;
  int rows = (int)(avail / per_row);
  rows &= ~127;
  if (rows > 1280) rows = 1280;
  if (rows < 128) rows = 128;
  short* h = (short*)p;

  hipMemsetAsync(token_of_slot, 0xFF, (size_t)(NE * CAP) * 4, stream);
  moe_router<<<SEQ / 4, 256, 0, stream>>>(x, Wg, bg, routes, pmax);
  moe_scan<<<1, 1024, 0, stream>>>(routes, slot_of_token, token_of_slot, counts);
  moe_gather<<<NE * CAP, 256, 0, stream>>>(x, token_of_slot, Xd);
  moe_convT<<<dim3(FFD / 32, DIM / 32, NE), dim3(32, 8), 0, stream>>>(W1, W1bT, DIM, FFD);
  moe_convT<<<dim3(DIM / 32, FFD / 32, NE), dim3(32, 8), 0, stream>>>(W2, W2bT, FFD, DIM);

  for (int r0 = 0; r0 < CAP; r0 += rows) {
    int cr = (CAP - r0 < rows) ? (CAP - r0) : rows;
    int mch = cr / 128;
    moe_gemm1<<<32 * 8 * mch, 256, 0, stream>>>(Xd, W1bT, b1, h, counts, r0, rows, mch);
    moe_gemm2<<<8 * 8 * mch, 256, 0, stream>>>(h, W2bT, b2, token_of_slot, pmax, out,
                                               counts, r0, rows, mch);
  }
  moe_fixup<<<SEQ / 8, 256, 0, stream>>>(x, slot_of_token, out);
}

// Round 4
// 1155.340 us; speedup vs baseline: 1.3345x; 1.3345x over previous
//
#include <hip/hip_runtime.h>
#include <stdint.h>

#define SEQ 32768
#define DIM 1024
#define FFD 4096
#define NE 8
#define CAP 5120

typedef __bf16 bf16x8 __attribute__((ext_vector_type(8)));
typedef float f32x4 __attribute__((ext_vector_type(4)));

__device__ __forceinline__ short f2bf(float f) {
  uint32_t u = __float_as_uint(f);
  uint32_t r = (u + 0x7fffu + ((u >> 16) & 1u)) >> 16;
  return (short)r;
}

__device__ __forceinline__ void async_copy16(const void* g, void* lds) {
  __builtin_amdgcn_global_load_lds((const __attribute__((address_space(1))) void*)g,
                                   (__attribute__((address_space(3))) void*)lds, 16, 0, 0);
}

// A&S 7.1.26 erf: max abs err 1.5e-7, branchless
__device__ __forceinline__ float fast_erf(float y) {
  float ay = fabsf(y);
  float t = __frcp_rn(1.0f + 0.3275911f * ay);
  float p = 1.061405429f;
  p = p * t - 1.453152027f;
  p = p * t + 1.421413741f;
  p = p * t - 0.284496736f;
  p = p * t + 0.254829592f;
  p = p * t;
  float e = __expf(-ay * ay);
  float r = 1.0f - p * e;
  return copysignf(r, y);
}

// ---------------- router: logits in f64, argmax + p_max ----------------
__global__ __launch_bounds__(256) void moe_router(const float* __restrict__ x,
                                                  const float* __restrict__ Wg,
                                                  const float* __restrict__ bg,
                                                  int* __restrict__ routes,
                                                  float* __restrict__ pmax) {
  int token = blockIdx.x * 4 + (threadIdx.x >> 6);
  int lane = threadIdx.x & 63;
  const float* xr = x + (size_t)token * DIM;
  double acc[NE];
#pragma unroll
  for (int e = 0; e < NE; e++) acc[e] = 0.0;
#pragma unroll
  for (int i = 0; i < DIM / 64; i++) {
    int d = i * 64 + lane;
    double xv = (double)xr[d];
    const float* wr = Wg + (size_t)d * NE;
    float4 w0 = *(const float4*)(wr);
    float4 w1 = *(const float4*)(wr + 4);
    acc[0] += xv * (double)w0.x; acc[1] += xv * (double)w0.y;
    acc[2] += xv * (double)w0.z; acc[3] += xv * (double)w0.w;
    acc[4] += xv * (double)w1.x; acc[5] += xv * (double)w1.y;
    acc[6] += xv * (double)w1.z; acc[7] += xv * (double)w1.w;
  }
#pragma unroll
  for (int e = 0; e < NE; e++) {
#pragma unroll
    for (int off = 32; off >= 1; off >>= 1) acc[e] += __shfl_xor(acc[e], off);
  }
  if (lane == 0) {
    double l[NE];
#pragma unroll
    for (int e = 0; e < NE; e++) l[e] = acc[e] + (double)bg[e];
    int am = 0;
#pragma unroll
    for (int e = 1; e < NE; e++) if (l[e] > l[am]) am = e;
    double s = 0.0;
#pragma unroll
    for (int e = 0; e < NE; e++) s += exp(l[e] - l[am]);
    routes[token] = am;
    pmax[token] = (float)(1.0 / s);
  }
}

// ---------------- scan: per-expert FCFS positions ----------------
__global__ __launch_bounds__(1024) void moe_scan(const int* __restrict__ routes,
                                                 int* __restrict__ slot_of_token,
                                                 int* __restrict__ token_of_slot,
                                                 int* __restrict__ counts) {
  __shared__ int wtot[16][NE];
  __shared__ int woff[16][NE];
  int t = threadIdx.x, lane = t & 63, w = t >> 6;
  int cnt[NE];
#pragma unroll
  for (int e = 0; e < NE; e++) cnt[e] = 0;
  int base = t * 32;
  for (int i = 0; i < 32; i++) {
    int r = routes[base + i];
#pragma unroll
    for (int e = 0; e < NE; e++) cnt[e] += (r == e) ? 1 : 0;
  }
  int incl[NE];
#pragma unroll
  for (int e = 0; e < NE; e++) {
    int v = cnt[e];
#pragma unroll
    for (int off = 1; off < 64; off <<= 1) {
      int o = __shfl_up(v, off);
      if (lane >= off) v += o;
    }
    incl[e] = v;
    if (lane == 63) wtot[w][e] = v;
  }
  __syncthreads();
  if (t < NE) {
    int run = 0;
    for (int ww = 0; ww < 16; ww++) {
      int tmp = wtot[ww][t];
      woff[ww][t] = run;
      run += tmp;
    }
    counts[t] = run;
  }
  __syncthreads();
  int pos[NE];
#pragma unroll
  for (int e = 0; e < NE; e++) pos[e] = woff[w][e] + incl[e] - cnt[e];
  for (int i = 0; i < 32; i++) {
    int tok = base + i;
    int r = routes[tok];
    int p = 0;
#pragma unroll
    for (int e = 0; e < NE; e++)
      if (r == e) { p = pos[e]; pos[e] = p + 1; }
    bool kept = p < CAP;
    int slot = kept ? r * CAP + p : NE * CAP;
    slot_of_token[tok] = slot;
    if (kept) token_of_slot[slot] = tok;
  }
}

// ---------------- gather dispatch buffer (bf16), zeros for empty slots ----------------
__global__ __launch_bounds__(256) void moe_gather(const float* __restrict__ x,
                                                  const int* __restrict__ token_of_slot,
                                                  short* __restrict__ Xd) {
  int slot = blockIdx.x;
  int tok = token_of_slot[slot];
  int t = threadIdx.x;
  short* dst = Xd + (size_t)slot * DIM + t * 4;
  short4 v;
  if (tok < 0) {
    v.x = 0; v.y = 0; v.z = 0; v.w = 0;
  } else {
    float4 f = *(const float4*)(x + (size_t)tok * DIM + t * 4);
    v.x = f2bf(f.x); v.y = f2bf(f.y); v.z = f2bf(f.z); v.w = f2bf(f.w);
  }
  *(short4*)dst = v;
}

// ---------------- convert f32 [E][K][N] -> bf16 [E][N][K] ----------------
__global__ __launch_bounds__(256) void moe_convT(const float* __restrict__ W,
                                                 short* __restrict__ WT, int K, int N) {
  __shared__ float tile[32][33];
  int e = blockIdx.z;
  const float* We = W + (size_t)e * K * N;
  short* WTe = WT + (size_t)e * K * N;
  int n0 = blockIdx.x * 32, k0 = blockIdx.y * 32;
  int tx = threadIdx.x, ty = threadIdx.y;
#pragma unroll
  for (int i = 0; i < 4; i++)
    tile[ty + i * 8][tx] = We[(size_t)(k0 + ty + i * 8) * N + n0 + tx];
  __syncthreads();
#pragma unroll
  for (int i = 0; i < 4; i++)
    WTe[(size_t)(n0 + ty + i * 8) * K + k0 + tx] = f2bf(tile[tx][ty + i * 8]);
}

// ================= 256x256 8-phase GEMM machinery =================
// LDS (shorts): A buf0 [0,16384), A buf1 [16384,32768), B buf0 [32768,49152), B buf1 [49152,65536)
// Tile: 256 rows x 64 K-elems. Rows reordered: A lrow = mh*128 + wr*64 + sub(64);
// B lrow = nh*128 + wc*32 + sub(32). Swizzle: kbyte ^= (lrow&7)<<4, applied on the
// global SOURCE (pre-swizzle) and on ds_read -- gload_lds dest stays linear (rule #21).

__device__ __forceinline__ void stage_half(const short* __restrict__ g, int ld, int ktile,
                                           short* dst, int half, bool isA, int t) {
#pragma unroll
  for (int q = 0; q < 2; q++) {
    int li = q * 512 + t;
    int lrow = half * 128 + (li >> 3);
    int local = lrow & 127;
    int grow = isA ? ((local >> 6) * 128 + half * 64 + (local & 63))
                   : ((local >> 5) * 64 + half * 32 + (local & 31));
    int cb = ((li & 7) * 16) ^ ((lrow & 7) << 4);
    const char* src = (const char*)g + (size_t)grow * ld * 2 + ktile * 128 + cb;
    async_copy16(src, dst + half * 8192 + li * 8);
  }
}

__device__ __forceinline__ bf16x8 read_frag(const short* base, int lrow, int kbyte) {
  int cb = kbyte ^ ((lrow & 7) << 4);
  return *(const bf16x8*)((const char*)base + lrow * 128 + cb);
}

__device__ __forceinline__ void mainloop256(const short* __restrict__ Ag, int lda,
                                            const short* __restrict__ Bg, int ldb,
                                            int NT, short* smem, f32x4 acc[8][4],
                                            int wr, int wc, int l, int t) {
  short* A0 = smem;
  short* A1 = smem + 16384;
  short* B0 = smem + 32768;
  short* B1 = smem + 49152;
  // prologue: tile0 fully, tile1 all but B_nh1 (queue order matters for vmcnt math)
  stage_half(Ag, lda, 0, A0, 0, true, t);
  stage_half(Bg, ldb, 0, B0, 0, false, t);
  stage_half(Ag, lda, 0, A0, 1, true, t);
  stage_half(Bg, ldb, 0, B0, 1, false, t);
  stage_half(Ag, lda, 1, A1, 0, true, t);
  stage_half(Bg, ldb, 1, B1, 0, false, t);
  stage_half(Ag, lda, 1, A1, 1, true, t);
  asm volatile("s_waitcnt vmcnt(6)" ::: "memory");
  __builtin_amdgcn_s_barrier();

  const int kh16 = (l >> 4) * 16;
  const int l15 = l & 15;
  for (int T = 0; T < NT; T++) {
    short* Ac = (T & 1) ? A1 : A0;
    short* Bc = (T & 1) ? B1 : B0;
    short* Bn = (T & 1) ? B0 : B1;
    bf16x8 a[4][2], b0[2][2], b1[2][2];
    // ---- P1: Q(mh0,nh0): 8 A-reads + 4 B-reads; stage (T+1).B_nh1 -> next buf
#pragma unroll
    for (int mf = 0; mf < 4; mf++)
#pragma unroll
      for (int kk = 0; kk < 2; kk++)
        a[mf][kk] = read_frag(Ac, wr * 64 + mf * 16 + l15, kk * 64 + kh16);
#pragma unroll
    for (int nf = 0; nf < 2; nf++)
#pragma unroll
      for (int kk = 0; kk < 2; kk++)
        b0[nf][kk] = read_frag(Bc, wc * 32 + nf * 16 + l15, kk * 64 + kh16);
    if (T + 1 < NT) stage_half(Bg, ldb, T + 1, Bn, 1, false, t);
    __builtin_amdgcn_s_barrier();
    __builtin_amdgcn_s_setprio(1);
#pragma unroll
    for (int mf = 0; mf < 4; mf++)
#pragma unroll
      for (int nf = 0; nf < 2; nf++)
#pragma unroll
        for (int kk = 0; kk < 2; kk++)
          acc[mf][nf] = __builtin_amdgcn_mfma_f32_16x16x32_bf16(a[mf][kk], b0[nf][kk], acc[mf][nf], 0, 0, 0);
    __builtin_amdgcn_s_setprio(0);
    __builtin_amdgcn_s_barrier();
    // ---- P2: Q(mh0,nh1): 4 B-reads; stage (T+2).A_mh0 -> cur buf (A_mh0 consumed in P1)
#pragma unroll
    for (int nf = 0; nf < 2; nf++)
#pragma unroll
      for (int kk = 0; kk < 2; kk++)
        b1[nf][kk] = read_frag(Bc, 128 + wc * 32 + nf * 16 + l15, kk * 64 + kh16);
    if (T + 2 < NT) stage_half(Ag, lda, T + 2, Ac, 0, true, t);
    __builtin_amdgcn_s_barrier();
    __builtin_amdgcn_s_setprio(1);
#pragma unroll
    for (int mf = 0; mf < 4; mf++)
#pragma unroll
      for (int nf = 0; nf < 2; nf++)
#pragma unroll
        for (int kk = 0; kk < 2; kk++)
          acc[mf][nf + 2] = __builtin_amdgcn_mfma_f32_16x16x32_bf16(a[mf][kk], b1[nf][kk], acc[mf][nf + 2], 0, 0, 0);
    __builtin_amdgcn_s_setprio(0);
    __builtin_amdgcn_s_barrier();
    // ---- P3: Q(mh1,nh1): 8 A-reads; stage (T+2).B_nh0 -> cur (B_nh0 consumed in P1)
#pragma unroll
    for (int mf = 0; mf < 4; mf++)
#pragma unroll
      for (int kk = 0; kk < 2; kk++)
        a[mf][kk] = read_frag(Ac, 128 + wr * 64 + mf * 16 + l15, kk * 64 + kh16);
    if (T + 2 < NT) stage_half(Bg, ldb, T + 2, Bc, 0, false, t);
    __builtin_amdgcn_s_barrier();
    __builtin_amdgcn_s_setprio(1);
#pragma unroll
    for (int mf = 0; mf < 4; mf++)
#pragma unroll
      for (int nf = 0; nf < 2; nf++)
#pragma unroll
        for (int kk = 0; kk < 2; kk++)
          acc[mf + 4][nf + 2] = __builtin_amdgcn_mfma_f32_16x16x32_bf16(a[mf][kk], b1[nf][kk], acc[mf + 4][nf + 2], 0, 0, 0);
    __builtin_amdgcn_s_setprio(0);
    __builtin_amdgcn_s_barrier();
    // ---- P4: Q(mh1,nh0): 0 reads; stage (T+2).A_mh1 -> cur (A_mh1 consumed in P3)
    if (T + 2 < NT) stage_half(Ag, lda, T + 2, Ac, 1, true, t);
    __builtin_amdgcn_s_barrier();
    __builtin_amdgcn_s_setprio(1);
#pragma unroll
    for (int mf = 0; mf < 4; mf++)
#pragma unroll
      for (int nf = 0; nf < 2; nf++)
#pragma unroll
        for (int kk = 0; kk < 2; kk++)
          acc[mf + 4][nf] = __builtin_amdgcn_mfma_f32_16x16x32_bf16(a[mf][kk], b0[nf][kk], acc[mf + 4][nf], 0, 0, 0);
    __builtin_amdgcn_s_setprio(0);
    // counted vmcnt: 3 half-tiles (6 loads) in flight in steady state
    if (T + 2 < NT) asm volatile("s_waitcnt vmcnt(6)" ::: "memory");
    else            asm volatile("s_waitcnt vmcnt(0)" ::: "memory");
    __builtin_amdgcn_s_barrier();
  }
  asm volatile("s_waitcnt vmcnt(0) lgkmcnt(0)" ::: "memory");
  __builtin_amdgcn_s_barrier();
}

// ---------------- GEMM1: h = gelu(Xd @ W1 + b1), bf16 out ----------------
__global__ __launch_bounds__(512, 2) void moe_gemm1(const short* __restrict__ Xd,
                                                    const short* __restrict__ W1bT,
                                                    const float* __restrict__ b1,
                                                    short* __restrict__ h,
                                                    const int* __restrict__ counts,
                                                    int m_base, int rows, int mch) {
  extern __shared__ short smem[];
  int bid = blockIdx.x;
  int xcd = bid & 7;
  int idx = bid >> 3;
  int nn = idx & 15;
  int mlin = (idx >> 4) * 8 + xcd;
  int e = mlin / mch;
  int mm = mlin - e * mch;
  int cnt = counts[e]; if (cnt > CAP) cnt = CAP;
  int m0 = m_base + mm * 256;
  if (m0 >= cnt) return;
  int n0 = nn * 256;
  int t = threadIdx.x, l = t & 63, wid = t >> 6;
  int wr = wid >> 2, wc = wid & 3;
  const short* Ag = Xd + ((size_t)e * CAP + m0) * DIM;
  const short* Bg = W1bT + ((size_t)e * FFD + n0) * DIM;
  f32x4 acc[8][4];
#pragma unroll
  for (int mf = 0; mf < 8; mf++)
#pragma unroll
    for (int nf = 0; nf < 4; nf++) acc[mf][nf] = (f32x4){0.f, 0.f, 0.f, 0.f};
  mainloop256(Ag, DIM, Bg, DIM, DIM / 64, smem, acc, wr, wc, l, t);

  // epilogue: gelu -> bf16 tile staged in LDS (128 x 272 padded), coalesced write
  float bias[4];
#pragma unroll
  for (int nf = 0; nf < 4; nf++)
    bias[nf] = b1[(size_t)e * FFD + n0 + wc * 64 + nf * 16 + (l & 15)];
#pragma unroll
  for (int half = 0; half < 2; half++) {
    if (wr == half) {
#pragma unroll
      for (int mf = 0; mf < 8; mf++)
#pragma unroll
        for (int nf = 0; nf < 4; nf++)
#pragma unroll
          for (int j = 0; j < 4; j++) {
            int lr = mf * 16 + (l >> 4) * 4 + j;
            int lc = wc * 64 + nf * 16 + (l & 15);
            float v = acc[mf][nf][j] + bias[nf];
            float g = 0.5f * v * (1.0f + fast_erf(v * 0.70710678118654752f));
            smem[lr * 272 + lc] = f2bf(g);
          }
    }
    asm volatile("s_waitcnt lgkmcnt(0)" ::: "memory");
    __builtin_amdgcn_s_barrier();
    int r = t >> 2, c0 = (t & 3) * 64;
    short* hrow = h + ((size_t)e * rows + (m0 - m_base) + half * 128 + r) * FFD + n0 + c0;
    const short* srow = smem + r * 272 + c0;
#pragma unroll
    for (int i = 0; i < 8; i++)
      *(int4*)(hrow + i * 8) = *(const int4*)(srow + i * 8);
    asm volatile("s_waitcnt lgkmcnt(0)" ::: "memory");
    __builtin_amdgcn_s_barrier();
  }
}

// ---------------- GEMM2: out[token] = (h @ W2 + b2) * p_max, scatter ----------------
__global__ __launch_bounds__(512, 2) void moe_gemm2(const short* __restrict__ h,
                                                    const short* __restrict__ W2bT,
                                                    const float* __restrict__ b2,
                                                    const int* __restrict__ token_of_slot,
                                                    const float* __restrict__ pmax,
                                                    float* __restrict__ out,
                                                    const int* __restrict__ counts,
                                                    int m_base, int rows, int mch) {
  extern __shared__ short smem[];
  int bid = blockIdx.x;
  int xcd = bid & 7;
  int idx = bid >> 3;
  int nn = idx & 3;
  int mlin = (idx >> 2) * 8 + xcd;
  int e = mlin / mch;
  int mm = mlin - e * mch;
  int cnt = counts[e]; if (cnt > CAP) cnt = CAP;
  int m0 = m_base + mm * 256;
  if (m0 >= cnt) return;
  int n0 = nn * 256;
  int t = threadIdx.x, l = t & 63, wid = t >> 6;
  int wr = wid >> 2, wc = wid & 3;
  const short* Ag = h + ((size_t)e * rows + (m0 - m_base)) * FFD;
  const short* Bg = W2bT + ((size_t)e * DIM + n0) * FFD;
  f32x4 acc[8][4];
#pragma unroll
  for (int mf = 0; mf < 8; mf++)
#pragma unroll
    for (int nf = 0; nf < 4; nf++) acc[mf][nf] = (f32x4){0.f, 0.f, 0.f, 0.f};
  mainloop256(Ag, FFD, Bg, FFD, FFD / 64, smem, acc, wr, wc, l, t);

  float* ftile = (float*)smem;  // 128 x 256 f32 = 128 KB
  float bias[4];
#pragma unroll
  for (int nf = 0; nf < 4; nf++)
    bias[nf] = b2[(size_t)e * DIM + n0 + wc * 64 + nf * 16 + (l & 15)];
#pragma unroll
  for (int half = 0; half < 2; half++) {
    if (wr == half) {
#pragma unroll
      for (int mf = 0; mf < 8; mf++)
#pragma unroll
        for (int nf = 0; nf < 4; nf++)
#pragma unroll
          for (int j = 0; j < 4; j++) {
            int lr = mf * 16 + (l >> 4) * 4 + j;
            int lc = wc * 64 + nf * 16 + (l & 15);
            ftile[lr * 256 + lc] = acc[mf][nf][j] + bias[nf];
          }
    }
    asm volatile("s_waitcnt lgkmcnt(0)" ::: "memory");
    __builtin_amdgcn_s_barrier();
    int r = t >> 2, c0 = (t & 3) * 64;
    int slotrow = m0 + half * 128 + r;
    int tok = token_of_slot[e * CAP + slotrow];
    if (tok >= 0) {
      float f = pmax[tok];
      float* orow = out + (size_t)tok * DIM + n0 + c0;
      const float* srow = ftile + r * 256 + c0;
#pragma unroll
      for (int i = 0; i < 16; i++) {
        float4 v = *(const float4*)(srow + i * 4);
        v.x *= f; v.y *= f; v.z *= f; v.w *= f;
        *(float4*)(orow + i * 4) = v;
      }
    }
    asm volatile("s_waitcnt lgkmcnt(0)" ::: "memory");
    __builtin_amdgcn_s_barrier();
  }
}

// ---------------- dropped tokens: passthrough x ----------------
__global__ __launch_bounds__(256) void moe_fixup(const float* __restrict__ x,
                                                 const int* __restrict__ slot_of_token,
                                                 float* __restrict__ out) {
  int tok8 = blockIdx.x * 8 + (threadIdx.x >> 5);
  int lane32 = threadIdx.x & 31;
  if (slot_of_token[tok8] != NE * CAP) return;
#pragma unroll
  for (int i = 0; i < 8; i++) {
    int c = (i * 32 + lane32) * 4;
    float4 v = *(const float4*)(x + (size_t)tok8 * DIM + c);
    *(float4*)(out + (size_t)tok8 * DIM + c) = v;
  }
}

extern "C" void kernel_launch(void* const* d_in, const int* in_sizes, int n_in,
                              void* d_out, int out_size, void* d_ws, size_t ws_size,
                              hipStream_t stream) {
  (void)in_sizes; (void)n_in; (void)out_size;
  const float* x  = (const float*)d_in[0];
  const float* Wg = (const float*)d_in[1];
  const float* bg = (const float*)d_in[2];
  const float* W1 = (const float*)d_in[3];
  const float* b1 = (const float*)d_in[4];
  const float* W2 = (const float*)d_in[5];
  const float* b2 = (const float*)d_in[6];
  float* out = (float*)d_out;

  static bool attr_set = false;
  if (!attr_set) {
    hipFuncSetAttribute((const void*)moe_gemm1, hipFuncAttributeMaxDynamicSharedMemorySize, 131072);
    hipFuncSetAttribute((const void*)moe_gemm2, hipFuncAttributeMaxDynamicSharedMemorySize, 131072);
    attr_set = true;
  }

  char* p = (char*)d_ws;
  auto carve = [&](size_t bytes) -> char* {
    char* r = p;
    p += (bytes + 255) & ~(size_t)255;
    return r;
  };
  short* W1bT = (short*)carve((size_t)NE * DIM * FFD * 2);
  short* W2bT = (short*)carve((size_t)NE * DIM * FFD * 2);
  short* Xd   = (short*)carve((size_t)NE * CAP * DIM * 2);
  int* routes = (int*)carve((size_t)SEQ * 4);
  float* pmax = (float*)carve((size_t)SEQ * 4);
  int* slot_of_token = (int*)carve((size_t)SEQ * 4);
  int* token_of_slot = (int*)carve((size_t)(NE * CAP) * 4);
  int* counts = (int*)carve(256);
  size_t fixed = (size_t)(p - (char*)d_ws);

  // h chunk rows per expert: as large as ws allows, multiple of 256
  size_t avail = (ws_size > fixed + 4096) ? (ws_size - fixed - 4096) : 0;
  size_t per_row = (size_t)NE * FFD * 2;
  int rows = (int)(avail / per_row);
  rows &= ~255;
  if (rows > CAP) rows = CAP;
  if (rows < 256) rows = 256;
  short* h = (short*)p;

  hipMemsetAsync(token_of_slot, 0xFF, (size_t)(NE * CAP) * 4, stream);
  moe_router<<<SEQ / 4, 256, 0, stream>>>(x, Wg, bg, routes, pmax);
  moe_scan<<<1, 1024, 0, stream>>>(routes, slot_of_token, token_of_slot, counts);
  moe_gather<<<NE * CAP, 256, 0, stream>>>(x, token_of_slot, Xd);
  moe_convT<<<dim3(FFD / 32, DIM / 32, NE), dim3(32, 8), 0, stream>>>(W1, W1bT, DIM, FFD);
  moe_convT<<<dim3(DIM / 32, FFD / 32, NE), dim3(32, 8), 0, stream>>>(W2, W2bT, FFD, DIM);

  for (int r0 = 0; r0 < CAP; r0 += rows) {
    int cr = (CAP - r0 < rows) ? (CAP - r0) : rows;
    int mch = cr / 256;
    moe_gemm1<<<16 * NE * mch, 512, 131072, stream>>>(Xd, W1bT, b1, h, counts, r0, rows, mch);
    moe_gemm2<<<4 * NE * mch, 512, 131072, stream>>>(h, W2bT, b2, token_of_slot, pmax, out,
                                                     counts, r0, rows, mch);
  }
  moe_fixup<<<SEQ / 8, 256, 0, stream>>>(x, slot_of_token, out);
}

// Round 5
// 1055.214 us; speedup vs baseline: 1.4611x; 1.0949x over previous
//
#include <hip/hip_runtime.h>
#include <stdint.h>

#define SEQ 32768
#define DIM 1024
#define FFD 4096
#define NE 8
#define CAP 5120

typedef __bf16 bf16x8 __attribute__((ext_vector_type(8)));
typedef float f32x4 __attribute__((ext_vector_type(4)));

__device__ __forceinline__ short f2bf(float f) {
  uint32_t u = __float_as_uint(f);
  uint32_t r = (u + 0x7fffu + ((u >> 16) & 1u)) >> 16;
  return (short)r;
}

__device__ __forceinline__ void async_copy16(const void* g, void* lds) {
  __builtin_amdgcn_global_load_lds((const __attribute__((address_space(1))) void*)g,
                                   (__attribute__((address_space(3))) void*)lds, 16, 0, 0);
}

// A&S 7.1.26 erf: max abs err 1.5e-7, branchless
__device__ __forceinline__ float fast_erf(float y) {
  float ay = fabsf(y);
  float t = __frcp_rn(1.0f + 0.3275911f * ay);
  float p = 1.061405429f;
  p = p * t - 1.453152027f;
  p = p * t + 1.421413741f;
  p = p * t - 0.284496736f;
  p = p * t + 0.254829592f;
  p = p * t;
  float e = __expf(-ay * ay);
  float r = 1.0f - p * e;
  return copysignf(r, y);
}

// ---------------- router: logits in f64, argmax + p_max ----------------
__global__ __launch_bounds__(256) void moe_router(const float* __restrict__ x,
                                                  const float* __restrict__ Wg,
                                                  const float* __restrict__ bg,
                                                  int* __restrict__ routes,
                                                  float* __restrict__ pmax) {
  int token = blockIdx.x * 4 + (threadIdx.x >> 6);
  int lane = threadIdx.x & 63;
  const float* xr = x + (size_t)token * DIM;
  double acc[NE];
#pragma unroll
  for (int e = 0; e < NE; e++) acc[e] = 0.0;
#pragma unroll
  for (int i = 0; i < DIM / 64; i++) {
    int d = i * 64 + lane;
    double xv = (double)xr[d];
    const float* wr = Wg + (size_t)d * NE;
    float4 w0 = *(const float4*)(wr);
    float4 w1 = *(const float4*)(wr + 4);
    acc[0] += xv * (double)w0.x; acc[1] += xv * (double)w0.y;
    acc[2] += xv * (double)w0.z; acc[3] += xv * (double)w0.w;
    acc[4] += xv * (double)w1.x; acc[5] += xv * (double)w1.y;
    acc[6] += xv * (double)w1.z; acc[7] += xv * (double)w1.w;
  }
#pragma unroll
  for (int e = 0; e < NE; e++) {
#pragma unroll
    for (int off = 32; off >= 1; off >>= 1) acc[e] += __shfl_xor(acc[e], off);
  }
  if (lane == 0) {
    double l[NE];
#pragma unroll
    for (int e = 0; e < NE; e++) l[e] = acc[e] + (double)bg[e];
    int am = 0;
#pragma unroll
    for (int e = 1; e < NE; e++) if (l[e] > l[am]) am = e;
    double s = 0.0;
#pragma unroll
    for (int e = 0; e < NE; e++) s += exp(l[e] - l[am]);
    routes[token] = am;
    pmax[token] = (float)(1.0 / s);
  }
}

// ---------------- scan: per-expert FCFS positions ----------------
__global__ __launch_bounds__(1024) void moe_scan(const int* __restrict__ routes,
                                                 int* __restrict__ slot_of_token,
                                                 int* __restrict__ token_of_slot,
                                                 int* __restrict__ counts) {
  __shared__ int wtot[16][NE];
  __shared__ int woff[16][NE];
  int t = threadIdx.x, lane = t & 63, w = t >> 6;
  int cnt[NE];
#pragma unroll
  for (int e = 0; e < NE; e++) cnt[e] = 0;
  int base = t * 32;
  for (int i = 0; i < 32; i++) {
    int r = routes[base + i];
#pragma unroll
    for (int e = 0; e < NE; e++) cnt[e] += (r == e) ? 1 : 0;
  }
  int incl[NE];
#pragma unroll
  for (int e = 0; e < NE; e++) {
    int v = cnt[e];
#pragma unroll
    for (int off = 1; off < 64; off <<= 1) {
      int o = __shfl_up(v, off);
      if (lane >= off) v += o;
    }
    incl[e] = v;
    if (lane == 63) wtot[w][e] = v;
  }
  __syncthreads();
  if (t < NE) {
    int run = 0;
    for (int ww = 0; ww < 16; ww++) {
      int tmp = wtot[ww][t];
      woff[ww][t] = run;
      run += tmp;
    }
    counts[t] = run;
  }
  __syncthreads();
  int pos[NE];
#pragma unroll
  for (int e = 0; e < NE; e++) pos[e] = woff[w][e] + incl[e] - cnt[e];
  for (int i = 0; i < 32; i++) {
    int tok = base + i;
    int r = routes[tok];
    int p = 0;
#pragma unroll
    for (int e = 0; e < NE; e++)
      if (r == e) { p = pos[e]; pos[e] = p + 1; }
    bool kept = p < CAP;
    int slot = kept ? r * CAP + p : NE * CAP;
    slot_of_token[tok] = slot;
    if (kept) token_of_slot[slot] = tok;
  }
}

// ---------------- gather dispatch buffer (bf16), zeros for empty slots ----------------
__global__ __launch_bounds__(256) void moe_gather(const float* __restrict__ x,
                                                  const int* __restrict__ token_of_slot,
                                                  short* __restrict__ Xd) {
  int slot = blockIdx.x;
  int tok = token_of_slot[slot];
  int t = threadIdx.x;
  short* dst = Xd + (size_t)slot * DIM + t * 4;
  short4 v;
  if (tok < 0) {
    v.x = 0; v.y = 0; v.z = 0; v.w = 0;
  } else {
    float4 f = *(const float4*)(x + (size_t)tok * DIM + t * 4);
    v.x = f2bf(f.x); v.y = f2bf(f.y); v.z = f2bf(f.z); v.w = f2bf(f.w);
  }
  *(short4*)dst = v;
}

// ---------------- convert f32 [E][K][N] -> bf16 [E][N][K] ----------------
__global__ __launch_bounds__(256) void moe_convT(const float* __restrict__ W,
                                                 short* __restrict__ WT, int K, int N) {
  __shared__ float tile[32][33];
  int e = blockIdx.z;
  const float* We = W + (size_t)e * K * N;
  short* WTe = WT + (size_t)e * K * N;
  int n0 = blockIdx.x * 32, k0 = blockIdx.y * 32;
  int tx = threadIdx.x, ty = threadIdx.y;
#pragma unroll
  for (int i = 0; i < 4; i++)
    tile[ty + i * 8][tx] = We[(size_t)(k0 + ty + i * 8) * N + n0 + tx];
  __syncthreads();
#pragma unroll
  for (int i = 0; i < 4; i++)
    WTe[(size_t)(n0 + ty + i * 8) * K + k0 + tx] = f2bf(tile[tx][ty + i * 8]);
}

// ================= 256x256 8-phase GEMM mainloop, hoisted addressing =================
// LDS bytes: A buf0 [0,32768) A buf1 [32768,65536) B buf0 [65536,98304) B buf1 [98304,131072)
// (each buffer: half0 [0,16384) half1 [16384,32768) within its 32KB region)
// Swizzle: kbyte ^= (lrow&7)<<4 on global SOURCE (pre-swizzle) and on ds_read;
// gload_lds dest stays linear (rule #21). Issue order identical to the verified r4 loop.

__device__ __forceinline__ void mainloop256(const short* __restrict__ Ag, int lda,
                                            const short* __restrict__ Bg, int ldb,
                                            int NT, short* smem, f32x4 acc[8][4],
                                            int wr, int wc, int l, int t) {
  // ---- hoisted staging source pointers (advance +128B per staged tile) ----
  const int cb = ((t & 7) << 4) ^ (((t >> 3) & 7) << 4);
  const int rs = t >> 3;                         // 0..63
  const int rb = ((rs >> 5) << 6) + (rs & 31);   // B-row base
  const size_t la2 = (size_t)lda * 2, lb2 = (size_t)ldb * 2;
  const char* pa0q0 = (const char*)Ag + (size_t)(rs)       * la2 + cb;
  const char* pa0q1 = (const char*)Ag + (size_t)(128 + rs) * la2 + cb;
  const char* pa1q0 = (const char*)Ag + (size_t)(64 + rs)  * la2 + cb;
  const char* pa1q1 = (const char*)Ag + (size_t)(192 + rs) * la2 + cb;
  const char* pb0q0 = (const char*)Bg + (size_t)(rb)       * lb2 + cb;
  const char* pb0q1 = (const char*)Bg + (size_t)(128 + rb) * lb2 + cb;
  const char* pb1q0 = (const char*)Bg + (size_t)(32 + rb)  * lb2 + cb;
  const char* pb1q1 = (const char*)Bg + (size_t)(160 + rb) * lb2 + cb;
  short* dA = smem + t * 8;            // + q*4096 + half*8192 + sel*16384 (shorts)
  short* dB = smem + 32768 + t * 8;

  auto STG = [&](const char*& p0, const char*& p1, short* d) {
    async_copy16(p0, d);
    async_copy16(p1, d + 4096);
    p0 += 128; p1 += 128;
  };

  // prologue: tile0 full, tile1 all but B_h1 (same issue order as verified r4)
  STG(pa0q0, pa0q1, dA);
  STG(pb0q0, pb0q1, dB);
  STG(pa1q0, pa1q1, dA + 8192);
  STG(pb1q0, pb1q1, dB + 8192);
  STG(pa0q0, pa0q1, dA + 16384);
  STG(pb0q0, pb0q1, dB + 16384);
  STG(pa1q0, pa1q1, dA + 16384 + 8192);
  asm volatile("s_waitcnt vmcnt(6)" ::: "memory");
  __builtin_amdgcn_s_barrier();

  // ---- hoisted ds_read base pointers (constant offsets fold into ds_read imm) ----
  const int l15 = l & 15;
  const int kh16 = (l >> 4) << 4;
  const int swz = (l15 & 7) << 4;
  const char* paK0 = (const char*)smem + (wr * 64 + l15) * 128 + (kh16 ^ swz);
  const char* paK1 = (const char*)smem + (wr * 64 + l15) * 128 + ((64 + kh16) ^ swz);
  const char* pbK0 = (const char*)smem + 65536 + (wc * 32 + l15) * 128 + (kh16 ^ swz);
  const char* pbK1 = (const char*)smem + 65536 + (wc * 32 + l15) * 128 + ((64 + kh16) ^ swz);

  for (int T = 0; T < NT; T++) {
    const int selByte = (T & 1) << 15;          // current-buf byte offset
    const int selSh = (T & 1) << 14;            // shorts
    const int selShN = ((T + 1) & 1) << 14;
    const char* pa0 = paK0 + selByte;
    const char* pa1 = paK1 + selByte;
    const char* pb0 = pbK0 + selByte;
    const char* pb1 = pbK1 + selByte;
    bf16x8 a[4][2], b0[2][2], b1[2][2];
    // ---- P1: reads for Q(mh0,nh0); stage (T+1).B_h1 -> next buf
#pragma unroll
    for (int mf = 0; mf < 4; mf++) {
      a[mf][0] = *(const bf16x8*)(pa0 + mf * 2048);
      a[mf][1] = *(const bf16x8*)(pa1 + mf * 2048);
    }
#pragma unroll
    for (int nf = 0; nf < 2; nf++) {
      b0[nf][0] = *(const bf16x8*)(pb0 + nf * 2048);
      b0[nf][1] = *(const bf16x8*)(pb1 + nf * 2048);
    }
    if (T + 1 < NT) STG(pb1q0, pb1q1, dB + 8192 + selShN);
    __builtin_amdgcn_s_barrier();
    __builtin_amdgcn_s_setprio(1);
#pragma unroll
    for (int mf = 0; mf < 4; mf++)
#pragma unroll
      for (int nf = 0; nf < 2; nf++)
#pragma unroll
        for (int kk = 0; kk < 2; kk++)
          acc[mf][nf] = __builtin_amdgcn_mfma_f32_16x16x32_bf16(a[mf][kk], b0[nf][kk], acc[mf][nf], 0, 0, 0);
    __builtin_amdgcn_s_setprio(0);
    __builtin_amdgcn_s_barrier();
    // ---- P2: reads B half1; stage (T+2).A_h0 -> cur buf
#pragma unroll
    for (int nf = 0; nf < 2; nf++) {
      b1[nf][0] = *(const bf16x8*)(pb0 + 16384 + nf * 2048);
      b1[nf][1] = *(const bf16x8*)(pb1 + 16384 + nf * 2048);
    }
    if (T + 2 < NT) STG(pa0q0, pa0q1, dA + selSh);
    __builtin_amdgcn_s_barrier();
    __builtin_amdgcn_s_setprio(1);
#pragma unroll
    for (int mf = 0; mf < 4; mf++)
#pragma unroll
      for (int nf = 0; nf < 2; nf++)
#pragma unroll
        for (int kk = 0; kk < 2; kk++)
          acc[mf][nf + 2] = __builtin_amdgcn_mfma_f32_16x16x32_bf16(a[mf][kk], b1[nf][kk], acc[mf][nf + 2], 0, 0, 0);
    __builtin_amdgcn_s_setprio(0);
    __builtin_amdgcn_s_barrier();
    // ---- P3: reads A half1; stage (T+2).B_h0 -> cur buf
#pragma unroll
    for (int mf = 0; mf < 4; mf++) {
      a[mf][0] = *(const bf16x8*)(pa0 + 16384 + mf * 2048);
      a[mf][1] = *(const bf16x8*)(pa1 + 16384 + mf * 2048);
    }
    if (T + 2 < NT) STG(pb0q0, pb0q1, dB + selSh);
    __builtin_amdgcn_s_barrier();
    __builtin_amdgcn_s_setprio(1);
#pragma unroll
    for (int mf = 0; mf < 4; mf++)
#pragma unroll
      for (int nf = 0; nf < 2; nf++)
#pragma unroll
        for (int kk = 0; kk < 2; kk++)
          acc[mf + 4][nf + 2] = __builtin_amdgcn_mfma_f32_16x16x32_bf16(a[mf][kk], b1[nf][kk], acc[mf + 4][nf + 2], 0, 0, 0);
    __builtin_amdgcn_s_setprio(0);
    __builtin_amdgcn_s_barrier();
    // ---- P4: no reads; stage (T+2).A_h1 -> cur buf
    if (T + 2 < NT) STG(pa1q0, pa1q1, dA + 8192 + selSh);
    __builtin_amdgcn_s_barrier();
    __builtin_amdgcn_s_setprio(1);
#pragma unroll
    for (int mf = 0; mf < 4; mf++)
#pragma unroll
      for (int nf = 0; nf < 2; nf++)
#pragma unroll
        for (int kk = 0; kk < 2; kk++)
          acc[mf + 4][nf] = __builtin_amdgcn_mfma_f32_16x16x32_bf16(a[mf][kk], b0[nf][kk], acc[mf + 4][nf], 0, 0, 0);
    __builtin_amdgcn_s_setprio(0);
    if (T + 2 < NT) asm volatile("s_waitcnt vmcnt(6)" ::: "memory");
    else            asm volatile("s_waitcnt vmcnt(0)" ::: "memory");
    __builtin_amdgcn_s_barrier();
  }
  asm volatile("s_waitcnt vmcnt(0) lgkmcnt(0)" ::: "memory");
  __builtin_amdgcn_s_barrier();
}

// ---------------- GEMM1: h = gelu(Xd @ W1 + b1), bf16 out ----------------
__global__ __launch_bounds__(512, 2) void moe_gemm1(const short* __restrict__ Xd,
                                                    const short* __restrict__ W1bT,
                                                    const float* __restrict__ b1,
                                                    short* __restrict__ h,
                                                    const int* __restrict__ counts,
                                                    int m_base, int rows, int mch) {
  extern __shared__ short smem[];
  int bid = blockIdx.x;
  int xcd = bid & 7;
  int idx = bid >> 3;
  int nn = idx & 15;
  int mlin = (idx >> 4) * 8 + xcd;
  int e = mlin / mch;
  int mm = mlin - e * mch;
  int cnt = counts[e]; if (cnt > CAP) cnt = CAP;
  int m0 = m_base + mm * 256;
  if (m0 >= cnt) return;
  int n0 = nn * 256;
  int t = threadIdx.x, l = t & 63, wid = t >> 6;
  int wr = wid >> 2, wc = wid & 3;
  const short* Ag = Xd + ((size_t)e * CAP + m0) * DIM;
  const short* Bg = W1bT + ((size_t)e * FFD + n0) * DIM;
  f32x4 acc[8][4];
#pragma unroll
  for (int mf = 0; mf < 8; mf++)
#pragma unroll
    for (int nf = 0; nf < 4; nf++) acc[mf][nf] = (f32x4){0.f, 0.f, 0.f, 0.f};
  mainloop256(Ag, DIM, Bg, DIM, DIM / 64, smem, acc, wr, wc, l, t);

  // epilogue: full 256x256 bf16 tile in LDS (128 KB), all waves, single pass
  int l15 = l & 15;
  float bias[4];
#pragma unroll
  for (int nf = 0; nf < 4; nf++)
    bias[nf] = b1[(size_t)e * FFD + n0 + wc * 64 + nf * 16 + l15];
#pragma unroll
  for (int mf = 0; mf < 8; mf++)
#pragma unroll
    for (int nf = 0; nf < 4; nf++)
#pragma unroll
      for (int j = 0; j < 4; j++) {
        int lr = wr * 128 + mf * 16 + (l >> 4) * 4 + j;
        int lc = wc * 64 + nf * 16 + l15;
        float v = acc[mf][nf][j] + bias[nf];
        float g = 0.5f * v * (1.0f + fast_erf(v * 0.70710678118654752f));
        smem[lr * 256 + lc] = f2bf(g);
      }
  asm volatile("s_waitcnt lgkmcnt(0)" ::: "memory");
  __builtin_amdgcn_s_barrier();
  int r = t >> 1, c0 = (t & 1) * 128;
  short* hrow = h + ((size_t)e * rows + (m0 - m_base) + r) * FFD + n0 + c0;
  const short* srow = smem + r * 256 + c0;
#pragma unroll
  for (int i = 0; i < 16; i++)
    *(int4*)(hrow + i * 8) = *(const int4*)(srow + i * 8);
}

// ---------------- GEMM2: out[token] = (h @ W2 + b2) * p_max, scatter ----------------
__global__ __launch_bounds__(512, 2) void moe_gemm2(const short* __restrict__ h,
                                                    const short* __restrict__ W2bT,
                                                    const float* __restrict__ b2,
                                                    const int* __restrict__ token_of_slot,
                                                    const float* __restrict__ pmax,
                                                    float* __restrict__ out,
                                                    const int* __restrict__ counts,
                                                    int m_base, int rows, int mch) {
  extern __shared__ short smem[];
  int bid = blockIdx.x;
  int xcd = bid & 7;
  int idx = bid >> 3;
  int nn = idx & 3;
  int mlin = (idx >> 2) * 8 + xcd;
  int e = mlin / mch;
  int mm = mlin - e * mch;
  int cnt = counts[e]; if (cnt > CAP) cnt = CAP;
  int m0 = m_base + mm * 256;
  if (m0 >= cnt) return;
  int n0 = nn * 256;
  int t = threadIdx.x, l = t & 63, wid = t >> 6;
  int wr = wid >> 2, wc = wid & 3;
  const short* Ag = h + ((size_t)e * rows + (m0 - m_base)) * FFD;
  const short* Bg = W2bT + ((size_t)e * DIM + n0) * FFD;
  f32x4 acc[8][4];
#pragma unroll
  for (int mf = 0; mf < 8; mf++)
#pragma unroll
    for (int nf = 0; nf < 4; nf++) acc[mf][nf] = (f32x4){0.f, 0.f, 0.f, 0.f};
  mainloop256(Ag, FFD, Bg, FFD, FFD / 64, smem, acc, wr, wc, l, t);

  float* ftile = (float*)smem;  // 128 x 256 f32 = 128 KB
  int l15 = l & 15;
  float bias[4];
#pragma unroll
  for (int nf = 0; nf < 4; nf++)
    bias[nf] = b2[(size_t)e * DIM + n0 + wc * 64 + nf * 16 + l15];
#pragma unroll
  for (int half = 0; half < 2; half++) {
    if (wr == half) {
#pragma unroll
      for (int mf = 0; mf < 8; mf++)
#pragma unroll
        for (int nf = 0; nf < 4; nf++)
#pragma unroll
          for (int j = 0; j < 4; j++) {
            int lr = mf * 16 + (l >> 4) * 4 + j;
            int lc = wc * 64 + nf * 16 + l15;
            ftile[lr * 256 + lc] = acc[mf][nf][j] + bias[nf];
          }
    }
    asm volatile("s_waitcnt lgkmcnt(0)" ::: "memory");
    __builtin_amdgcn_s_barrier();
    int r = t >> 2, c0 = (t & 3) * 64;
    int slotrow = m0 + half * 128 + r;
    int tok = token_of_slot[e * CAP + slotrow];
    if (tok >= 0) {
      float f = pmax[tok];
      float* orow = out + (size_t)tok * DIM + n0 + c0;
      const float* srow = ftile + r * 256 + c0;
#pragma unroll
      for (int i = 0; i < 16; i++) {
        float4 v = *(const float4*)(srow + i * 4);
        v.x *= f; v.y *= f; v.z *= f; v.w *= f;
        *(float4*)(orow + i * 4) = v;
      }
    }
    asm volatile("s_waitcnt lgkmcnt(0)" ::: "memory");
    __builtin_amdgcn_s_barrier();
  }
}

// ---------------- dropped tokens: passthrough x ----------------
__global__ __launch_bounds__(256) void moe_fixup(const float* __restrict__ x,
                                                 const int* __restrict__ slot_of_token,
                                                 float* __restrict__ out) {
  int tok8 = blockIdx.x * 8 + (threadIdx.x >> 5);
  int lane32 = threadIdx.x & 31;
  if (slot_of_token[tok8] != NE * CAP) return;
#pragma unroll
  for (int i = 0; i < 8; i++) {
    int c = (i * 32 + lane32) * 4;
    float4 v = *(const float4*)(x + (size_t)tok8 * DIM + c);
    *(float4*)(out + (size_t)tok8 * DIM + c) = v;
  }
}

extern "C" void kernel_launch(void* const* d_in, const int* in_sizes, int n_in,
                              void* d_out, int out_size, void* d_ws, size_t ws_size,
                              hipStream_t stream) {
  (void)in_sizes; (void)n_in; (void)out_size;
  const float* x  = (const float*)d_in[0];
  const float* Wg = (const float*)d_in[1];
  const float* bg = (const float*)d_in[2];
  const float* W1 = (const float*)d_in[3];
  const float* b1 = (const float*)d_in[4];
  const float* W2 = (const float*)d_in[5];
  const float* b2 = (const float*)d_in[6];
  float* out = (float*)d_out;

  static bool attr_set = false;
  if (!attr_set) {
    hipFuncSetAttribute((const void*)moe_gemm1, hipFuncAttributeMaxDynamicSharedMemorySize, 131072);
    hipFuncSetAttribute((const void*)moe_gemm2, hipFuncAttributeMaxDynamicSharedMemorySize, 131072);
    attr_set = true;
  }

  char* p = (char*)d_ws;
  auto carve = [&](size_t bytes) -> char* {
    char* r = p;
    p += (bytes + 255) & ~(size_t)255;
    return r;
  };
  short* W1bT = (short*)carve((size_t)NE * DIM * FFD * 2);
  short* W2bT = (short*)carve((size_t)NE * DIM * FFD * 2);
  short* Xd   = (short*)carve((size_t)NE * CAP * DIM * 2);
  int* routes = (int*)carve((size_t)SEQ * 4);
  float* pmax = (float*)carve((size_t)SEQ * 4);
  int* slot_of_token = (int*)carve((size_t)SEQ * 4);
  int* token_of_slot = (int*)carve((size_t)(NE * CAP) * 4);
  int* counts = (int*)carve(256);
  size_t fixed = (size_t)(p - (char*)d_ws);

  size_t avail = (ws_size > fixed + 4096) ? (ws_size - fixed - 4096) : 0;
  size_t per_row = (size_t)NE * FFD * 2;
  int rows = (int)(avail / per_row);
  rows &= ~255;
  if (rows > CAP) rows = CAP;
  if (rows < 256) rows = 256;
  short* h = (short*)p;

  hipMemsetAsync(token_of_slot, 0xFF, (size_t)(NE * CAP) * 4, stream);
  moe_router<<<SEQ / 4, 256, 0, stream>>>(x, Wg, bg, routes, pmax);
  moe_scan<<<1, 1024, 0, stream>>>(routes, slot_of_token, token_of_slot, counts);
  moe_gather<<<NE * CAP, 256, 0, stream>>>(x, token_of_slot, Xd);
  moe_convT<<<dim3(FFD / 32, DIM / 32, NE), dim3(32, 8), 0, stream>>>(W1, W1bT, DIM, FFD);
  moe_convT<<<dim3(DIM / 32, FFD / 32, NE), dim3(32, 8), 0, stream>>>(W2, W2bT, FFD, DIM);

  for (int r0 = 0; r0 < CAP; r0 += rows) {
    int cr = (CAP - r0 < rows) ? (CAP - r0) : rows;
    int mch = cr / 256;
    moe_gemm1<<<16 * NE * mch, 512, 131072, stream>>>(Xd, W1bT, b1, h, counts, r0, rows, mch);
    moe_gemm2<<<4 * NE * mch, 512, 131072, stream>>>(h, W2bT, b2, token_of_slot, pmax, out,
                                                     counts, r0, rows, mch);
  }
  moe_fixup<<<SEQ / 8, 256, 0, stream>>>(x, slot_of_token, out);
}